// Round 1
// baseline (339.035 us; speedup 1.0000x reference)
//
#include <hip/hip_runtime.h>
#include <math.h>

#define NPTS 32768
#define C 64
#define K 16
#define NB2 64            // partial-reduction blocks for sred
#define BN_INV 0.99999500003749968f   // 1/sqrt(1+1e-5)

__device__ __forceinline__ float safediv_n2n(float a, float b) {
    float q = a / b;
    if (isnan(q)) return 0.0f;
    if (isinf(q)) return copysignf(3.402823466e38f, q);
    return q;
}

// ---------------------------------------------------------------------------
// K1: x_q = x^T @ Wq + bq ; y_k = y^T @ Wk + bk ; y_v = y^T @ Wv + bv
// grid (NPTS/64, 3), block 256.  Each wave: 16 rows, lane = output col j.
// Weight column held in 64 VGPRs; input rows read as uniform float4.
// ---------------------------------------------------------------------------
__global__ __launch_bounds__(256) void proj_kernel(
    const float* __restrict__ x, const float* __restrict__ y,
    const float* __restrict__ Wq, const float* __restrict__ bq,
    const float* __restrict__ Wk, const float* __restrict__ bk,
    const float* __restrict__ Wv, const float* __restrict__ bv,
    float* __restrict__ xq, float* __restrict__ yk, float* __restrict__ yv)
{
    const int dir = blockIdx.y;
    const float* __restrict__ in   = (dir == 0) ? x  : y;
    const float* __restrict__ W    = (dir == 0) ? Wq : (dir == 1) ? Wk : Wv;
    const float* __restrict__ bias = (dir == 0) ? bq : (dir == 1) ? bk : bv;
    float* __restrict__ out        = (dir == 0) ? xq : (dir == 1) ? yk : yv;

    const int j    = threadIdx.x & 63;
    const int wave = threadIdx.x >> 6;
    const int n0   = blockIdx.x * 64 + wave * 16;

    float wcol[C];
    #pragma unroll
    for (int c = 0; c < C; ++c) wcol[c] = W[c * C + j];

    float acc[16];
    const float b = bias[j];
    #pragma unroll
    for (int i = 0; i < 16; ++i) acc[i] = b;

    #pragma unroll
    for (int c = 0; c < C; ++c) {
        const float4* src = (const float4*)(in + c * NPTS + n0);
        float va[16];
        ((float4*)va)[0] = src[0];
        ((float4*)va)[1] = src[1];
        ((float4*)va)[2] = src[2];
        ((float4*)va)[3] = src[3];
        #pragma unroll
        for (int i = 0; i < 16; ++i) acc[i] = fmaf(va[i], wcol[c], acc[i]);
    }
    #pragma unroll
    for (int i = 0; i < 16; ++i) out[(n0 + i) * C + j] = acc[i];
}

// ---------------------------------------------------------------------------
// K1b: x_uni[m] = relu(bn(sum_j x_flat[m*64+j]*Wu[j] + bu))   (flat reshape!)
// ---------------------------------------------------------------------------
__global__ __launch_bounds__(256) void xuni_kernel(
    const float* __restrict__ x, const float* __restrict__ Wu,
    const float* __restrict__ bu, const float* __restrict__ gu,
    const float* __restrict__ bnu, float* __restrict__ xu)
{
    const int lane = threadIdx.x & 63;
    const int wave = threadIdx.x >> 6;
    const int m = blockIdx.x * 4 + wave;
    float v = x[m * 64 + lane] * Wu[lane];
    #pragma unroll
    for (int off = 32; off > 0; off >>= 1) v += __shfl_xor(v, off, 64);
    if (lane == 0) {
        float u = (v + bu[0]) * (gu[0] * BN_INV) + bnu[0];
        xu[m] = fmaxf(u, 0.0f);
    }
}

// ---------------------------------------------------------------------------
// K2: partial S[c][k] = sum_n (y_k[idx[n,k]][c] - x_q[n][c]) * xu[n]
// lane = c, 16 register accumulators per lane; skip n when xu[n]==0 (relu).
// ---------------------------------------------------------------------------
__global__ __launch_bounds__(256) void sred_kernel(
    const float* __restrict__ xq, const float* __restrict__ yk,
    const float* __restrict__ xu, const int* __restrict__ idx,
    float* __restrict__ partG)
{
    const int lane = threadIdx.x & 63;
    const int wave = threadIdx.x >> 6;
    const int gw = blockIdx.x * 4 + wave;
    const int nwv = NB2 * 4;
    float g[K];
    #pragma unroll
    for (int k = 0; k < K; ++k) g[k] = 0.0f;
    for (int n = gw; n < NPTS; n += nwv) {
        const float xuv = xu[n];
        if (xuv != 0.0f) {
            const float xqv = xq[n * C + lane];
            #pragma unroll
            for (int k = 0; k < K; ++k) {
                const int id = idx[n * K + k];
                g[k] = fmaf(yk[id * C + lane] - xqv, xuv, g[k]);
            }
        }
    }
    __shared__ float red[4][K][C];
    #pragma unroll
    for (int k = 0; k < K; ++k) red[wave][k][lane] = g[k];
    __syncthreads();
    if (wave == 0) {
        #pragma unroll
        for (int k = 0; k < K; ++k) {
            float s = red[0][k][lane] + red[1][k][lane] + red[2][k][lane] + red[3][k][lane];
            partG[blockIdx.x * (K * C) + k * C + lane] = s;
        }
    }
}

// ---------------------------------------------------------------------------
// K2b: reduce partials, softmax over k -> wd[c][k]  and  awdT[k][c]=a_p[k]*wd
// single block, 1024 threads (one per (k,c))
// ---------------------------------------------------------------------------
__global__ __launch_bounds__(1024) void wd_kernel(
    const float* __restrict__ partG, const float* __restrict__ a_p,
    float* __restrict__ wd, float* __restrict__ awdT)
{
    __shared__ float S[K][C];
    const int t = threadIdx.x;          // t = k*64 + c
    {
        float s = 0.0f;
        #pragma unroll 8
        for (int b = 0; b < NB2; ++b) s += partG[b * (K * C) + t];
        S[0][t] = s;
    }
    __syncthreads();
    if (t < C) {
        const int c = t;
        float v[K];
        float m = -3.402823466e38f;
        #pragma unroll
        for (int k = 0; k < K; ++k) { v[k] = S[k][c]; m = fmaxf(m, v[k]); }
        float sum = 0.0f;
        #pragma unroll
        for (int k = 0; k < K; ++k) { v[k] = expf(v[k] - m); sum += v[k]; }
        const float r = 1.0f / sum;
        #pragma unroll
        for (int k = 0; k < K; ++k) {
            const float wv = v[k] * r;
            wd[c * K + k] = wv;
            awdT[k * C + c] = a_p[k] * wv;
        }
    }
}

// ---------------------------------------------------------------------------
// K3: w_e[n][k] = softmax_k( sum_c y[c][n] * wd[c][k] )
// block = 1 wave = 64 points
// ---------------------------------------------------------------------------
__global__ __launch_bounds__(64) void we_kernel(
    const float* __restrict__ y, const float* __restrict__ wd,
    float* __restrict__ we)
{
    __shared__ float ys[C][C + 1];
    __shared__ float wds[C][K];
    const int lane = threadIdx.x;
    const int n0 = blockIdx.x * 64;
    for (int c = 0; c < C; ++c) ys[c][lane] = y[c * NPTS + n0 + lane];
    {
        const float4* s = (const float4*)(wd + lane * K);
        ((float4*)&wds[lane][0])[0] = s[0];
        ((float4*)&wds[lane][0])[1] = s[1];
        ((float4*)&wds[lane][0])[2] = s[2];
        ((float4*)&wds[lane][0])[3] = s[3];
    }
    __syncthreads();
    float L[K];
    #pragma unroll
    for (int k = 0; k < K; ++k) L[k] = 0.0f;
    for (int c = 0; c < C; ++c) {
        const float yv = ys[c][lane];
        float wa[K];
        ((float4*)wa)[0] = ((const float4*)&wds[c][0])[0];
        ((float4*)wa)[1] = ((const float4*)&wds[c][0])[1];
        ((float4*)wa)[2] = ((const float4*)&wds[c][0])[2];
        ((float4*)wa)[3] = ((const float4*)&wds[c][0])[3];
        #pragma unroll
        for (int k = 0; k < K; ++k) L[k] = fmaf(yv, wa[k], L[k]);
    }
    float m = L[0];
    #pragma unroll
    for (int k = 1; k < K; ++k) m = fmaxf(m, L[k]);
    float sum = 0.0f;
    #pragma unroll
    for (int k = 0; k < K; ++k) { L[k] = expf(L[k] - m); sum += L[k]; }
    const float r = 1.0f / sum;
    float* dst = we + (size_t)(n0 + lane) * K;
    ((float4*)dst)[0] = make_float4(L[0]*r, L[1]*r, L[2]*r, L[3]*r);
    ((float4*)dst)[1] = make_float4(L[4]*r, L[5]*r, L[6]*r, L[7]*r);
    ((float4*)dst)[2] = make_float4(L[8]*r, L[9]*r, L[10]*r, L[11]*r);
    ((float4*)dst)[3] = make_float4(L[12]*r, L[13]*r, L[14]*r, L[15]*r);
}

// ---------------------------------------------------------------------------
// K4 (hot): per point n (one wave, lane = channel c):
//   w = awdT + b_p * w_e ; two relu-BN + (16x64)@(64x64) layers (weights in
//   128 VGPRs, activations via per-wave LDS broadcast reads); softmax over k;
//   geometry features on lanes 0..15; out = sum_k (y_v_gather + p_r) * w
// ---------------------------------------------------------------------------
__global__ __launch_bounds__(256, 2) void main_kernel(
    const int* __restrict__ idx, const float* __restrict__ y_xyz,
    const float* __restrict__ yv_all, const float* __restrict__ we,
    const float* __restrict__ awdT,
    const float* __restrict__ b_p, const float* __restrict__ d_p,
    const float* __restrict__ Ww1, const float* __restrict__ bw1,
    const float* __restrict__ Ww2, const float* __restrict__ bw2,
    const float* __restrict__ gw1, const float* __restrict__ bw1b,
    const float* __restrict__ gw2, const float* __restrict__ bw2b,
    const float* __restrict__ Wa1, const float* __restrict__ ba1,
    const float* __restrict__ ga, const float* __restrict__ bna,
    const float* __restrict__ Wa2, const float* __restrict__ ba2,
    const float* __restrict__ Wp1, const float* __restrict__ bp1,
    const float* __restrict__ gp, const float* __restrict__ bnp,
    const float* __restrict__ Wp2, const float* __restrict__ bp2,
    float* __restrict__ out)
{
    const int lane = threadIdx.x & 63;
    const int wave = threadIdx.x >> 6;

    __shared__ float hs[4][K][C];     // per-wave activation staging
    __shared__ float geo[4][K][8];    // per-wave geometry results
    __shared__ float prm[36];         // small geometry params
    __shared__ float bp_s[K][C], dp_s[K][C], aw_s[K][C];

    for (int i = threadIdx.x; i < K * C; i += 256) {
        bp_s[0][i] = b_p[i];
        dp_s[0][i] = d_p[i];
        aw_s[0][i] = awdT[i];
    }
    if (threadIdx.x < 36) {
        const int t = threadIdx.x;
        float v;
        if (t < 9)       v = Wa1[t];
        else if (t < 12) v = ba1[t - 9];
        else if (t < 21) v = Wp1[t - 12];
        else if (t < 24) v = bp1[t - 21];
        else if (t < 27) v = ga[t - 24];
        else if (t < 30) v = bna[t - 27];
        else if (t < 33) v = gp[t - 30];
        else             v = bnp[t - 33];
        prm[t] = v;
    }
    __syncthreads();

    float w1c[C], w2c[C];
    #pragma unroll
    for (int c = 0; c < C; ++c) { w1c[c] = Ww1[c * C + lane]; w2c[c] = Ww2[c * C + lane]; }

    const float gs1 = gw1[lane] * BN_INV, bb1 = bw1b[lane], bw1c = bw1[lane];
    const float gs2 = gw2[lane] * BN_INV, bb2 = bw2b[lane], bw2c = bw2[lane];
    const float ba2c = ba2[lane], bp2c = bp2[lane];
    float wa2c[3], wp2c[3];
    #pragma unroll
    for (int d = 0; d < 3; ++d) { wa2c[d] = Wa2[d * C + lane]; wp2c[d] = Wp2[d * C + lane]; }

    const int gw = blockIdx.x * 4 + wave;
    const int nwv = gridDim.x * 4;

    for (int n = gw; n < NPTS; n += nwv) {
        // ---- geometry, lanes 0..15 (k = lane) ----
        if (lane < K) {
            const int k = lane;
            const int id = idx[n * K + k];
            const float sx = y_xyz[n], sy = y_xyz[NPTS + n], sz = y_xyz[2 * NPTS + n];
            const float px = y_xyz[id] - sx;
            const float py = y_xyz[NPTS + id] - sy;
            const float pz = y_xyz[2 * NPTS + id] - sz;
            const float ed  = sqrtf(px * px + py * py + pz * pz);
            const float exy = sqrtf(px * px + py * py);
            const float cose = safediv_n2n(exy, ed);
            const float cosa = safediv_n2n(py, exy);
            float* g = &geo[wave][k][0];
            #pragma unroll
            for (int d = 0; d < 3; ++d) {
                const float a = ed * prm[d] + cosa * prm[3 + d] + cose * prm[6 + d] + prm[9 + d];
                g[1 + d] = fmaxf(a * (prm[24 + d] * BN_INV) + prm[27 + d], 0.0f);
                const float p = px * prm[12 + d] + py * prm[15 + d] + pz * prm[18 + d] + prm[21 + d];
                g[4 + d] = fmaxf(p * (prm[30 + d] * BN_INV) + prm[33 + d], 0.0f);
            }
            g[0] = __int_as_float(id);
        }

        // ---- w init + bn/relu (layer-1 input) ----
        const float4* wer4 = (const float4*)(we + (size_t)n * K);
        float wearr[K];
        ((float4*)wearr)[0] = wer4[0];
        ((float4*)wearr)[1] = wer4[1];
        ((float4*)wearr)[2] = wer4[2];
        ((float4*)wearr)[3] = wer4[3];
        #pragma unroll
        for (int k = 0; k < K; ++k) {
            const float wv = fmaf(bp_s[k][lane], wearr[k], aw_s[k][lane]);
            hs[wave][k][lane] = fmaxf(fmaf(wv, gs1, bb1), 0.0f);
        }
        __syncthreads();

        // ---- layer 1 matmul ----
        float o[K];
        #pragma unroll
        for (int k = 0; k < K; ++k) o[k] = bw1c;
        #pragma unroll
        for (int c4 = 0; c4 < 16; ++c4) {
            #pragma unroll
            for (int k = 0; k < K; ++k) {
                const float4 hv = *(const float4*)&hs[wave][k][c4 * 4];
                o[k] = fmaf(hv.x, w1c[c4 * 4 + 0], o[k]);
                o[k] = fmaf(hv.y, w1c[c4 * 4 + 1], o[k]);
                o[k] = fmaf(hv.z, w1c[c4 * 4 + 2], o[k]);
                o[k] = fmaf(hv.w, w1c[c4 * 4 + 3], o[k]);
            }
        }

        // ---- layer 2 ----
        #pragma unroll
        for (int k = 0; k < K; ++k)
            hs[wave][k][lane] = fmaxf(fmaf(o[k], gs2, bb2), 0.0f);
        __syncthreads();
        #pragma unroll
        for (int k = 0; k < K; ++k) o[k] = bw2c;
        #pragma unroll
        for (int c4 = 0; c4 < 16; ++c4) {
            #pragma unroll
            for (int k = 0; k < K; ++k) {
                const float4 hv = *(const float4*)&hs[wave][k][c4 * 4];
                o[k] = fmaf(hv.x, w2c[c4 * 4 + 0], o[k]);
                o[k] = fmaf(hv.y, w2c[c4 * 4 + 1], o[k]);
                o[k] = fmaf(hv.z, w2c[c4 * 4 + 2], o[k]);
                o[k] = fmaf(hv.w, w2c[c4 * 4 + 3], o[k]);
            }
        }

        // ---- softmax over k ----
        float m = o[0];
        #pragma unroll
        for (int k = 1; k < K; ++k) m = fmaxf(m, o[k]);
        float sum = 0.0f;
        #pragma unroll
        for (int k = 0; k < K; ++k) { o[k] = __expf(o[k] - m); sum += o[k]; }
        const float r = 1.0f / sum;

        // ---- epilogue: out = sum_k (y_v_gather + p_r) * w ----
        float acc = 0.0f;
        #pragma unroll
        for (int k = 0; k < K; ++k) {
            const float4 g0 = *(const float4*)&geo[wave][k][0];
            const float4 g1 = *(const float4*)&geo[wave][k][4];
            const int id = __float_as_int(g0.x);
            const float afc = fmaf(g0.y, wa2c[0], fmaf(g0.z, wa2c[1], fmaf(g0.w, wa2c[2], ba2c)));
            float prc = fmaf(g1.x, wp2c[0], fmaf(g1.y, wp2c[1], fmaf(g1.z, wp2c[2], bp2c)));
            prc = fmaf(dp_s[k][lane], afc, prc);
            const float yvv = yv_all[(size_t)id * C + lane];
            acc = fmaf(yvv + prc, o[k] * r, acc);
        }
        out[(size_t)n * C + lane] = acc;
        __syncthreads();
    }
}

// ---------------------------------------------------------------------------
extern "C" void kernel_launch(void* const* d_in, const int* in_sizes, int n_in,
                              void* d_out, int out_size, void* d_ws, size_t ws_size,
                              hipStream_t stream)
{
    (void)in_sizes; (void)n_in; (void)out_size; (void)ws_size;
    const float* x     = (const float*)d_in[0];
    const float* y     = (const float*)d_in[1];
    const float* y_xyz = (const float*)d_in[2];
    const int*   idx   = (const int*)d_in[3];
    const float* Wq = (const float*)d_in[4];  const float* bq = (const float*)d_in[5];
    const float* Wk = (const float*)d_in[6];  const float* bk = (const float*)d_in[7];
    const float* Wv = (const float*)d_in[8];  const float* bv = (const float*)d_in[9];
    const float* Wu = (const float*)d_in[10]; const float* bu = (const float*)d_in[11];
    const float* gu = (const float*)d_in[12]; const float* bnu = (const float*)d_in[13];
    const float* Wp1 = (const float*)d_in[14]; const float* bp1 = (const float*)d_in[15];
    const float* gp  = (const float*)d_in[16]; const float* bnp = (const float*)d_in[17];
    const float* Wp2 = (const float*)d_in[18]; const float* bp2 = (const float*)d_in[19];
    const float* Wa1 = (const float*)d_in[20]; const float* ba1 = (const float*)d_in[21];
    const float* ga  = (const float*)d_in[22]; const float* bna = (const float*)d_in[23];
    const float* Wa2 = (const float*)d_in[24]; const float* ba2 = (const float*)d_in[25];
    const float* gw1 = (const float*)d_in[26]; const float* bw1b = (const float*)d_in[27];
    const float* Ww1 = (const float*)d_in[28]; const float* bw1 = (const float*)d_in[29];
    const float* gw2 = (const float*)d_in[30]; const float* bw2b = (const float*)d_in[31];
    const float* Ww2 = (const float*)d_in[32]; const float* bw2 = (const float*)d_in[33];
    const float* a_p = (const float*)d_in[34];
    const float* b_p = (const float*)d_in[35];
    const float* d_p = (const float*)d_in[36];
    float* out = (float*)d_out;

    float* ws = (float*)d_ws;
    float* xq    = ws;                       // 2097152 floats (dead after sred)
    float* we    = ws;                       // aliases xq (written after sred)
    float* yk    = ws + 2097152;             // 2097152
    float* yv    = ws + 2 * 2097152;         // 2097152
    float* xu    = ws + 3 * 2097152;         // 32768
    float* partG = xu + NPTS;                // NB2*1024 = 65536
    float* wd    = partG + NB2 * K * C;      // 1024
    float* awdT  = wd + C * K;               // 1024

    proj_kernel<<<dim3(NPTS / 64, 3), 256, 0, stream>>>(x, y, Wq, bq, Wk, bk, Wv, bv, xq, yk, yv);
    xuni_kernel<<<NPTS / 4, 256, 0, stream>>>(x, Wu, bu, gu, bnu, xu);
    sred_kernel<<<NB2, 256, 0, stream>>>(xq, yk, xu, idx, partG);
    wd_kernel<<<1, 1024, 0, stream>>>(partG, a_p, wd, awdT);
    we_kernel<<<NPTS / 64, 64, 0, stream>>>(y, wd, we);
    main_kernel<<<512, 256, 0, stream>>>(idx, y_xyz, yv, we, awdT, b_p, d_p,
        Ww1, bw1, Ww2, bw2, gw1, bw1b, gw2, bw2b,
        Wa1, ba1, ga, bna, Wa2, ba2, Wp1, bp1, gp, bnp, Wp2, bp2, out);
}

// Round 2
// 269.216 us; speedup vs baseline: 1.2593x; 1.2593x over previous
//
#include <hip/hip_runtime.h>
#include <math.h>

#define NPTS 32768
#define C 64
#define K 16
#define NB2 64            // partial-reduction blocks for sred
#define NTAB 512          // table cells for the per-k PWL function F_kc(t)
#define BN_INV 0.99999500003749968f   // 1/sqrt(1+1e-5)

__device__ __forceinline__ float safediv_n2n(float a, float b) {
    float q = a / b;
    if (isnan(q)) return 0.0f;
    if (isinf(q)) return copysignf(3.402823466e38f, q);
    return q;
}

// ---------------------------------------------------------------------------
// K1: x_q = x^T @ Wq + bq ; y_k = y^T @ Wk + bk ; y_v = y^T @ Wv + bv
// ---------------------------------------------------------------------------
__global__ __launch_bounds__(256) void proj_kernel(
    const float* __restrict__ x, const float* __restrict__ y,
    const float* __restrict__ Wq, const float* __restrict__ bq,
    const float* __restrict__ Wk, const float* __restrict__ bk,
    const float* __restrict__ Wv, const float* __restrict__ bv,
    float* __restrict__ xq, float* __restrict__ yk, float* __restrict__ yv)
{
    const int dir = blockIdx.y;
    const float* __restrict__ in   = (dir == 0) ? x  : y;
    const float* __restrict__ W    = (dir == 0) ? Wq : (dir == 1) ? Wk : Wv;
    const float* __restrict__ bias = (dir == 0) ? bq : (dir == 1) ? bk : bv;
    float* __restrict__ out        = (dir == 0) ? xq : (dir == 1) ? yk : yv;

    const int j    = threadIdx.x & 63;
    const int wave = threadIdx.x >> 6;
    const int n0   = blockIdx.x * 64 + wave * 16;

    float wcol[C];
    #pragma unroll
    for (int c = 0; c < C; ++c) wcol[c] = W[c * C + j];

    float acc[16];
    const float b = bias[j];
    #pragma unroll
    for (int i = 0; i < 16; ++i) acc[i] = b;

    #pragma unroll
    for (int c = 0; c < C; ++c) {
        const float4* src = (const float4*)(in + c * NPTS + n0);
        float va[16];
        ((float4*)va)[0] = src[0];
        ((float4*)va)[1] = src[1];
        ((float4*)va)[2] = src[2];
        ((float4*)va)[3] = src[3];
        #pragma unroll
        for (int i = 0; i < 16; ++i) acc[i] = fmaf(va[i], wcol[c], acc[i]);
    }
    #pragma unroll
    for (int i = 0; i < 16; ++i) out[(n0 + i) * C + j] = acc[i];
}

// ---------------------------------------------------------------------------
// K1b: x_uni[m] = relu(bn(sum_j x_flat[m*64+j]*Wu[j] + bu))   (flat reshape!)
// ---------------------------------------------------------------------------
__global__ __launch_bounds__(256) void xuni_kernel(
    const float* __restrict__ x, const float* __restrict__ Wu,
    const float* __restrict__ bu, const float* __restrict__ gu,
    const float* __restrict__ bnu, float* __restrict__ xu)
{
    const int lane = threadIdx.x & 63;
    const int wave = threadIdx.x >> 6;
    const int m = blockIdx.x * 4 + wave;
    float v = x[m * 64 + lane] * Wu[lane];
    #pragma unroll
    for (int off = 32; off > 0; off >>= 1) v += __shfl_xor(v, off, 64);
    if (lane == 0) {
        float u = (v + bu[0]) * (gu[0] * BN_INV) + bnu[0];
        xu[m] = fmaxf(u, 0.0f);
    }
}

// ---------------------------------------------------------------------------
// K2: partial S[c][k] = sum_n (y_k[idx[n,k]][c] - x_q[n][c]) * xu[n]
// ---------------------------------------------------------------------------
__global__ __launch_bounds__(256) void sred_kernel(
    const float* __restrict__ xq, const float* __restrict__ yk,
    const float* __restrict__ xu, const int* __restrict__ idx,
    float* __restrict__ partG)
{
    const int lane = threadIdx.x & 63;
    const int wave = threadIdx.x >> 6;
    const int gw = blockIdx.x * 4 + wave;
    const int nwv = NB2 * 4;
    float g[K];
    #pragma unroll
    for (int k = 0; k < K; ++k) g[k] = 0.0f;
    for (int n = gw; n < NPTS; n += nwv) {
        const float xuv = xu[n];
        if (xuv != 0.0f) {
            const float xqv = xq[n * C + lane];
            #pragma unroll
            for (int k = 0; k < K; ++k) {
                const int id = idx[n * K + k];
                g[k] = fmaf(yk[id * C + lane] - xqv, xuv, g[k]);
            }
        }
    }
    __shared__ float red[4][K][C];
    #pragma unroll
    for (int k = 0; k < K; ++k) red[wave][k][lane] = g[k];
    __syncthreads();
    if (wave == 0) {
        #pragma unroll
        for (int k = 0; k < K; ++k) {
            float s = red[0][k][lane] + red[1][k][lane] + red[2][k][lane] + red[3][k][lane];
            partG[blockIdx.x * (K * C) + k * C + lane] = s;
        }
    }
}

// ---------------------------------------------------------------------------
// K2b: reduce partials, softmax over k -> wd[c][k]  and  awdT[k][c]=a_p[k]*wd
// ---------------------------------------------------------------------------
__global__ __launch_bounds__(1024) void wd_kernel(
    const float* __restrict__ partG, const float* __restrict__ a_p,
    float* __restrict__ wd, float* __restrict__ awdT)
{
    __shared__ float S[K][C];
    const int t = threadIdx.x;          // t = k*64 + c
    {
        float s = 0.0f;
        #pragma unroll 8
        for (int b = 0; b < NB2; ++b) s += partG[b * (K * C) + t];
        S[0][t] = s;
    }
    __syncthreads();
    if (t < C) {
        const int c = t;
        float v[K];
        float m = -3.402823466e38f;
        #pragma unroll
        for (int k = 0; k < K; ++k) { v[k] = S[k][c]; m = fmaxf(m, v[k]); }
        float sum = 0.0f;
        #pragma unroll
        for (int k = 0; k < K; ++k) { v[k] = expf(v[k] - m); sum += v[k]; }
        const float r = 1.0f / sum;
        #pragma unroll
        for (int k = 0; k < K; ++k) {
            const float wv = v[k] * r;
            wd[c * K + k] = wv;
            awdT[k * C + c] = a_p[k] * wv;
        }
    }
}

// ---------------------------------------------------------------------------
// K3: w_e[n][k] = softmax_k( sum_c y[c][n] * wd[c][k] )
// ---------------------------------------------------------------------------
__global__ __launch_bounds__(64) void we_kernel(
    const float* __restrict__ y, const float* __restrict__ wd,
    float* __restrict__ we)
{
    __shared__ float ys[C][C + 1];
    __shared__ float wds[C][K];
    const int lane = threadIdx.x;
    const int n0 = blockIdx.x * 64;
    for (int c = 0; c < C; ++c) ys[c][lane] = y[c * NPTS + n0 + lane];
    {
        const float4* s = (const float4*)(wd + lane * K);
        ((float4*)&wds[lane][0])[0] = s[0];
        ((float4*)&wds[lane][0])[1] = s[1];
        ((float4*)&wds[lane][0])[2] = s[2];
        ((float4*)&wds[lane][0])[3] = s[3];
    }
    __syncthreads();
    float L[K];
    #pragma unroll
    for (int k = 0; k < K; ++k) L[k] = 0.0f;
    for (int c = 0; c < C; ++c) {
        const float yv = ys[c][lane];
        float wa[K];
        ((float4*)wa)[0] = ((const float4*)&wds[c][0])[0];
        ((float4*)wa)[1] = ((const float4*)&wds[c][0])[1];
        ((float4*)wa)[2] = ((const float4*)&wds[c][0])[2];
        ((float4*)wa)[3] = ((const float4*)&wds[c][0])[3];
        #pragma unroll
        for (int k = 0; k < K; ++k) L[k] = fmaf(yv, wa[k], L[k]);
    }
    float m = L[0];
    #pragma unroll
    for (int k = 1; k < K; ++k) m = fmaxf(m, L[k]);
    float sum = 0.0f;
    #pragma unroll
    for (int k = 0; k < K; ++k) { L[k] = expf(L[k] - m); sum += L[k]; }
    const float r = 1.0f / sum;
    float* dst = we + (size_t)(n0 + lane) * K;
    ((float4*)dst)[0] = make_float4(L[0]*r, L[1]*r, L[2]*r, L[3]*r);
    ((float4*)dst)[1] = make_float4(L[4]*r, L[5]*r, L[6]*r, L[7]*r);
    ((float4*)dst)[2] = make_float4(L[8]*r, L[9]*r, L[10]*r, L[11]*r);
    ((float4*)dst)[3] = make_float4(L[12]*r, L[13]*r, L[14]*r, L[15]*r);
}

// ---------------------------------------------------------------------------
// K3b: tabulate F_kc(t) = layer2(relu(bn2(layer1(relu(bn1(aw + bp*t))))))
// at t = i/NTAB, i = 0..NTAB.  tab[k][i][c].  One wave per block; wave
// handles 16 consecutive i for one k; weight columns in VGPRs.
// The 2-layer map is piecewise-linear in t, so lerp on this table is
// accurate to ~1e-6 (breakpoint slope-changes ~(0.05)^2, cell width 1/512).
// ---------------------------------------------------------------------------
__global__ __launch_bounds__(64) void tab_kernel(
    const float* __restrict__ awdT, const float* __restrict__ b_p,
    const float* __restrict__ Ww1, const float* __restrict__ bw1,
    const float* __restrict__ Ww2, const float* __restrict__ bw2,
    const float* __restrict__ gw1, const float* __restrict__ bw1b,
    const float* __restrict__ gw2, const float* __restrict__ bw2b,
    float* __restrict__ tab)
{
    const int lane = threadIdx.x;
    const int k  = blockIdx.y;
    const int i0 = blockIdx.x * 16;

    const float aw = awdT[k * C + lane];
    const float bp = b_p[k * C + lane];
    const float gs1 = gw1[lane] * BN_INV, bb1 = bw1b[lane], bw1c = bw1[lane];
    const float gs2 = gw2[lane] * BN_INV, bb2 = bw2b[lane], bw2c = bw2[lane];

    float w1c[C], w2c[C];
    #pragma unroll
    for (int c = 0; c < C; ++c) { w1c[c] = Ww1[c * C + lane]; w2c[c] = Ww2[c * C + lane]; }

    __shared__ float hs[16][C];

    #pragma unroll
    for (int r = 0; r < 16; ++r) {
        const float t = (float)(i0 + r) * (1.0f / NTAB);
        const float wv = fmaf(bp, t, aw);
        hs[r][lane] = fmaxf(fmaf(wv, gs1, bb1), 0.0f);
    }
    __syncthreads();

    float o[16];
    #pragma unroll
    for (int r = 0; r < 16; ++r) o[r] = bw1c;
    #pragma unroll
    for (int c4 = 0; c4 < 16; ++c4) {
        #pragma unroll
        for (int r = 0; r < 16; ++r) {
            const float4 hv = *(const float4*)&hs[r][c4 * 4];
            o[r] = fmaf(hv.x, w1c[c4 * 4 + 0], o[r]);
            o[r] = fmaf(hv.y, w1c[c4 * 4 + 1], o[r]);
            o[r] = fmaf(hv.z, w1c[c4 * 4 + 2], o[r]);
            o[r] = fmaf(hv.w, w1c[c4 * 4 + 3], o[r]);
        }
    }
    __syncthreads();
    #pragma unroll
    for (int r = 0; r < 16; ++r)
        hs[r][lane] = fmaxf(fmaf(o[r], gs2, bb2), 0.0f);
    __syncthreads();
    #pragma unroll
    for (int r = 0; r < 16; ++r) o[r] = bw2c;
    #pragma unroll
    for (int c4 = 0; c4 < 16; ++c4) {
        #pragma unroll
        for (int r = 0; r < 16; ++r) {
            const float4 hv = *(const float4*)&hs[r][c4 * 4];
            o[r] = fmaf(hv.x, w2c[c4 * 4 + 0], o[r]);
            o[r] = fmaf(hv.y, w2c[c4 * 4 + 1], o[r]);
            o[r] = fmaf(hv.z, w2c[c4 * 4 + 2], o[r]);
            o[r] = fmaf(hv.w, w2c[c4 * 4 + 3], o[r]);
        }
    }
    #pragma unroll
    for (int r = 0; r < 16; ++r) {
        const int i = i0 + r;
        if (i <= NTAB) tab[(k * (NTAB + 1) + i) * C + lane] = o[r];
    }
}

// ---------------------------------------------------------------------------
// K4 (hot): per point n (one wave, lane = channel c):
//   w2[k] via table lerp (t = we[n][k] is wave-uniform -> coalesced 256B
//   L2-resident reads); softmax over k; geometry on lanes 0..15 shared via
//   per-wave LDS (wave-synchronous, no barriers); epilogue gathers y_v.
// ---------------------------------------------------------------------------
__global__ __launch_bounds__(256) void main2_kernel(
    const int* __restrict__ idx, const float* __restrict__ y_xyz,
    const float* __restrict__ yv_all, const float* __restrict__ we,
    const float* __restrict__ tab, const float* __restrict__ d_p,
    const float* __restrict__ Wa1, const float* __restrict__ ba1,
    const float* __restrict__ ga, const float* __restrict__ bna,
    const float* __restrict__ Wa2, const float* __restrict__ ba2,
    const float* __restrict__ Wp1, const float* __restrict__ bp1,
    const float* __restrict__ gp, const float* __restrict__ bnp,
    const float* __restrict__ Wp2, const float* __restrict__ bp2,
    float* __restrict__ out)
{
    const int lane = threadIdx.x & 63;
    const int wave = threadIdx.x >> 6;

    __shared__ float geo[4][K][8];    // per-wave geometry results
    __shared__ float prm[36];         // small geometry params

    if (threadIdx.x < 36) {
        const int t = threadIdx.x;
        float v;
        if (t < 9)       v = Wa1[t];
        else if (t < 12) v = ba1[t - 9];
        else if (t < 21) v = Wp1[t - 12];
        else if (t < 24) v = bp1[t - 21];
        else if (t < 27) v = ga[t - 24];
        else if (t < 30) v = bna[t - 27];
        else if (t < 33) v = gp[t - 30];
        else             v = bnp[t - 33];
        prm[t] = v;
    }
    __syncthreads();

    const float ba2c = ba2[lane], bp2c = bp2[lane];
    float wa2c[3], wp2c[3];
    #pragma unroll
    for (int d = 0; d < 3; ++d) { wa2c[d] = Wa2[d * C + lane]; wp2c[d] = Wp2[d * C + lane]; }
    float dpk[K];
    #pragma unroll
    for (int k = 0; k < K; ++k) dpk[k] = d_p[k * C + lane];

    const int gw = blockIdx.x * 4 + wave;
    const int nwv = gridDim.x * 4;

    for (int n = gw; n < NPTS; n += nwv) {
        // ---- geometry, lanes 0..15 (k = lane); per-wave LDS, wave-ordered ----
        if (lane < K) {
            const int k = lane;
            const int id = idx[n * K + k];
            const float sx = y_xyz[n], sy = y_xyz[NPTS + n], sz = y_xyz[2 * NPTS + n];
            const float px = y_xyz[id] - sx;
            const float py = y_xyz[NPTS + id] - sy;
            const float pz = y_xyz[2 * NPTS + id] - sz;
            const float ed  = sqrtf(px * px + py * py + pz * pz);
            const float exy = sqrtf(px * px + py * py);
            const float cose = safediv_n2n(exy, ed);
            const float cosa = safediv_n2n(py, exy);
            float* g = &geo[wave][k][0];
            #pragma unroll
            for (int d = 0; d < 3; ++d) {
                const float a = ed * prm[d] + cosa * prm[3 + d] + cose * prm[6 + d] + prm[9 + d];
                g[1 + d] = fmaxf(a * (prm[24 + d] * BN_INV) + prm[27 + d], 0.0f);
                const float p = px * prm[12 + d] + py * prm[15 + d] + pz * prm[18 + d] + prm[21 + d];
                g[4 + d] = fmaxf(p * (prm[30 + d] * BN_INV) + prm[33 + d], 0.0f);
            }
            g[0] = __int_as_float(id);
        }

        // ---- w2[k] via table lerp (t uniform per wave) ----
        const float4* wer4 = (const float4*)(we + (size_t)n * K);
        float wearr[K];
        ((float4*)wearr)[0] = wer4[0];
        ((float4*)wearr)[1] = wer4[1];
        ((float4*)wearr)[2] = wer4[2];
        ((float4*)wearr)[3] = wer4[3];

        float w2[K];
        #pragma unroll
        for (int k = 0; k < K; ++k) {
            const float u = wearr[k] * (float)NTAB;
            int ic = (int)u;
            ic = (ic < 0) ? 0 : (ic > NTAB - 1 ? NTAB - 1 : ic);
            const float f = u - (float)ic;
            const float* tp = tab + ((size_t)(k * (NTAB + 1) + ic) << 6) + lane;
            const float v0 = tp[0];
            const float v1 = tp[C];
            w2[k] = fmaf(f, v1 - v0, v0);
        }

        // ---- softmax over k ----
        float m = w2[0];
        #pragma unroll
        for (int k = 1; k < K; ++k) m = fmaxf(m, w2[k]);
        float sum = 0.0f;
        #pragma unroll
        for (int k = 0; k < K; ++k) { w2[k] = __expf(w2[k] - m); sum += w2[k]; }
        const float r = 1.0f / sum;

        // ---- epilogue: out = sum_k (y_v_gather + p_r) * w ----
        float acc = 0.0f;
        #pragma unroll
        for (int k = 0; k < K; ++k) {
            const float4 g0 = *(const float4*)&geo[wave][k][0];
            const float4 g1 = *(const float4*)&geo[wave][k][4];
            const int id = __float_as_int(g0.x);
            const float afc = fmaf(g0.y, wa2c[0], fmaf(g0.z, wa2c[1], fmaf(g0.w, wa2c[2], ba2c)));
            float prc = fmaf(g1.x, wp2c[0], fmaf(g1.y, wp2c[1], fmaf(g1.z, wp2c[2], bp2c)));
            prc = fmaf(dpk[k], afc, prc);
            const float yvv = yv_all[(size_t)id * C + lane];
            acc = fmaf(yvv + prc, w2[k] * r, acc);
        }
        out[(size_t)n * C + lane] = acc;
    }
}

// ---------------------------------------------------------------------------
extern "C" void kernel_launch(void* const* d_in, const int* in_sizes, int n_in,
                              void* d_out, int out_size, void* d_ws, size_t ws_size,
                              hipStream_t stream)
{
    (void)in_sizes; (void)n_in; (void)out_size; (void)ws_size;
    const float* x     = (const float*)d_in[0];
    const float* y     = (const float*)d_in[1];
    const float* y_xyz = (const float*)d_in[2];
    const int*   idx   = (const int*)d_in[3];
    const float* Wq = (const float*)d_in[4];  const float* bq = (const float*)d_in[5];
    const float* Wk = (const float*)d_in[6];  const float* bk = (const float*)d_in[7];
    const float* Wv = (const float*)d_in[8];  const float* bv = (const float*)d_in[9];
    const float* Wu = (const float*)d_in[10]; const float* bu = (const float*)d_in[11];
    const float* gu = (const float*)d_in[12]; const float* bnu = (const float*)d_in[13];
    const float* Wp1 = (const float*)d_in[14]; const float* bp1 = (const float*)d_in[15];
    const float* gp  = (const float*)d_in[16]; const float* bnp = (const float*)d_in[17];
    const float* Wp2 = (const float*)d_in[18]; const float* bp2 = (const float*)d_in[19];
    const float* Wa1 = (const float*)d_in[20]; const float* ba1 = (const float*)d_in[21];
    const float* ga  = (const float*)d_in[22]; const float* bna = (const float*)d_in[23];
    const float* Wa2 = (const float*)d_in[24]; const float* ba2 = (const float*)d_in[25];
    const float* gw1 = (const float*)d_in[26]; const float* bw1b = (const float*)d_in[27];
    const float* Ww1 = (const float*)d_in[28]; const float* bw1 = (const float*)d_in[29];
    const float* gw2 = (const float*)d_in[30]; const float* bw2b = (const float*)d_in[31];
    const float* Ww2 = (const float*)d_in[32]; const float* bw2 = (const float*)d_in[33];
    const float* a_p = (const float*)d_in[34];
    const float* b_p = (const float*)d_in[35];
    const float* d_p = (const float*)d_in[36];
    float* out = (float*)d_out;

    float* ws = (float*)d_ws;
    float* xq    = ws;                       // 2097152 floats (dead after sred)
    float* we    = ws;                       // aliases xq (written after sred)
    float* yk    = ws + 2097152;             // 2097152 (dead after sred)
    float* tab   = ws + 2097152;             // aliases yk; 16*513*64 = 525312 floats
    float* yv    = ws + 2 * 2097152;         // 2097152
    float* xu    = ws + 3 * 2097152;         // 32768
    float* partG = xu + NPTS;                // NB2*1024 = 65536
    float* wd    = partG + NB2 * K * C;      // 1024
    float* awdT  = wd + C * K;               // 1024

    proj_kernel<<<dim3(NPTS / 64, 3), 256, 0, stream>>>(x, y, Wq, bq, Wk, bk, Wv, bv, xq, yk, yv);
    xuni_kernel<<<NPTS / 4, 256, 0, stream>>>(x, Wu, bu, gu, bnu, xu);
    sred_kernel<<<NB2, 256, 0, stream>>>(xq, yk, xu, idx, partG);
    wd_kernel<<<1, 1024, 0, stream>>>(partG, a_p, wd, awdT);
    we_kernel<<<NPTS / 64, 64, 0, stream>>>(y, wd, we);
    tab_kernel<<<dim3(33, 16), 64, 0, stream>>>(awdT, b_p, Ww1, bw1, Ww2, bw2,
                                                gw1, bw1b, gw2, bw2b, tab);
    main2_kernel<<<2048, 256, 0, stream>>>(idx, y_xyz, yv, we, tab, d_p,
        Wa1, ba1, ga, bna, Wa2, ba2, Wp1, bp1, gp, bnp, Wp2, bp2, out);
}

// Round 3
// 150.507 us; speedup vs baseline: 2.2526x; 1.7887x over previous
//
#include <hip/hip_runtime.h>
#include <hip/hip_bf16.h>
#include <math.h>

#define NPTS 32768
#define C 64
#define K 16
#define NB2 512           // sred partial blocks
#define NB2R 64           // after sred2 hierarchical reduce
#define NTAB 512          // table cells for the per-k PWL function F_kc(t)
#define BN_INV 0.99999500003749968f   // 1/sqrt(1+1e-5)

__device__ __forceinline__ float safediv_n2n(float a, float b) {
    float q = a / b;
    if (isnan(q)) return 0.0f;
    if (isinf(q)) return copysignf(3.402823466e38f, q);
    return q;
}

// ---------------------------------------------------------------------------
// K1: dir 0/1/2: x_q | y_k | y_v(bf16) projections. dir 3: xuni + xyz pack.
// grid (512, 4), block 256.
// ---------------------------------------------------------------------------
__global__ __launch_bounds__(256) void proj_kernel(
    const float* __restrict__ x, const float* __restrict__ y,
    const float* __restrict__ y_xyz,
    const float* __restrict__ Wq, const float* __restrict__ bq,
    const float* __restrict__ Wk, const float* __restrict__ bk,
    const float* __restrict__ Wv, const float* __restrict__ bv,
    const float* __restrict__ Wu, const float* __restrict__ bu,
    const float* __restrict__ gu, const float* __restrict__ bnu,
    float* __restrict__ xq, float* __restrict__ yk,
    __hip_bfloat16* __restrict__ yvb, float* __restrict__ xu,
    float4* __restrict__ pk)
{
    const int dir  = blockIdx.y;
    const int lane = threadIdx.x & 63;
    const int wave = threadIdx.x >> 6;

    if (dir == 3) {
        // ---- xuni: 16 rows per wave ----
        const float wul = Wu[lane];
        const float bnscale = gu[0] * BN_INV;
        const float bu0 = bu[0], bnu0 = bnu[0];
        #pragma unroll 4
        for (int i = 0; i < 16; ++i) {
            const int m = blockIdx.x * 64 + wave * 16 + i;
            float v = x[m * 64 + lane] * wul;
            #pragma unroll
            for (int off = 32; off > 0; off >>= 1) v += __shfl_xor(v, off, 64);
            if (lane == 0) {
                float u = (v + bu0) * bnscale + bnu0;
                xu[m] = fmaxf(u, 0.0f);
            }
        }
        // ---- pack xyz (wave 0) ----
        if (wave == 0) {
            const int p = blockIdx.x * 64 + lane;
            pk[p] = make_float4(y_xyz[p], y_xyz[NPTS + p], y_xyz[2 * NPTS + p], 0.0f);
        }
        return;
    }

    const float* __restrict__ in   = (dir == 0) ? x  : y;
    const float* __restrict__ W    = (dir == 0) ? Wq : (dir == 1) ? Wk : Wv;
    const float* __restrict__ bias = (dir == 0) ? bq : (dir == 1) ? bk : bv;

    const int j  = lane;
    const int n0 = blockIdx.x * 64 + wave * 16;

    float wcol[C];
    #pragma unroll
    for (int c = 0; c < C; ++c) wcol[c] = W[c * C + j];

    float acc[16];
    const float b = bias[j];
    #pragma unroll
    for (int i = 0; i < 16; ++i) acc[i] = b;

    #pragma unroll
    for (int c = 0; c < C; ++c) {
        const float4* src = (const float4*)(in + c * NPTS + n0);
        float va[16];
        ((float4*)va)[0] = src[0];
        ((float4*)va)[1] = src[1];
        ((float4*)va)[2] = src[2];
        ((float4*)va)[3] = src[3];
        #pragma unroll
        for (int i = 0; i < 16; ++i) acc[i] = fmaf(va[i], wcol[c], acc[i]);
    }
    if (dir == 2) {
        #pragma unroll
        for (int i = 0; i < 16; ++i) yvb[(n0 + i) * C + j] = __float2bfloat16(acc[i]);
    } else {
        float* __restrict__ out = (dir == 0) ? xq : yk;
        #pragma unroll
        for (int i = 0; i < 16; ++i) out[(n0 + i) * C + j] = acc[i];
    }
}

// ---------------------------------------------------------------------------
// K2: partial S[c][k] = sum_n (y_k[idx[n,k]][c] - x_q[n][c]) * xu[n]
// NB2=512 blocks -> 2048 waves (8 waves/CU) for gather-latency hiding.
// ---------------------------------------------------------------------------
__global__ __launch_bounds__(256) void sred_kernel(
    const float* __restrict__ xq, const float* __restrict__ yk,
    const float* __restrict__ xu, const int* __restrict__ idx,
    float* __restrict__ partG)
{
    const int lane = threadIdx.x & 63;
    const int wave = threadIdx.x >> 6;
    const int gw = blockIdx.x * 4 + wave;
    const int nwv = NB2 * 4;
    float g[K];
    #pragma unroll
    for (int k = 0; k < K; ++k) g[k] = 0.0f;
    for (int n = gw; n < NPTS; n += nwv) {
        const float xuv = xu[n];
        if (xuv != 0.0f) {
            const float xqv = xq[n * C + lane];
            #pragma unroll
            for (int k = 0; k < K; ++k) {
                const int id = idx[n * K + k];
                g[k] = fmaf(yk[id * C + lane] - xqv, xuv, g[k]);
            }
        }
    }
    __shared__ float red[4][K][C];
    #pragma unroll
    for (int k = 0; k < K; ++k) red[wave][k][lane] = g[k];
    __syncthreads();
    if (wave == 0) {
        #pragma unroll
        for (int k = 0; k < K; ++k) {
            float s = red[0][k][lane] + red[1][k][lane] + red[2][k][lane] + red[3][k][lane];
            partG[blockIdx.x * (K * C) + k * C + lane] = s;
        }
    }
}

// ---------------------------------------------------------------------------
// K2a: hierarchical reduce 512 -> 64 partials (deterministic, no atomics)
// ---------------------------------------------------------------------------
__global__ __launch_bounds__(1024) void sred2_kernel(
    const float* __restrict__ partG, float* __restrict__ part2)
{
    const int j = blockIdx.x;       // 0..63
    const int t = threadIdx.x;      // 0..1023
    float s = 0.0f;
    #pragma unroll
    for (int i = 0; i < NB2 / NB2R; ++i)
        s += partG[(size_t)(j + NB2R * i) * (K * C) + t];
    part2[(size_t)j * (K * C) + t] = s;
}

// ---------------------------------------------------------------------------
// K2b: reduce 64 partials, softmax over k -> wd[c][k], awdT[k][c]=a_p[k]*wd
// ---------------------------------------------------------------------------
__global__ __launch_bounds__(1024) void wd_kernel(
    const float* __restrict__ part2, const float* __restrict__ a_p,
    float* __restrict__ wd, float* __restrict__ awdT)
{
    __shared__ float S[K][C];
    const int t = threadIdx.x;          // t = k*64 + c
    {
        float s = 0.0f;
        #pragma unroll 8
        for (int b = 0; b < NB2R; ++b) s += part2[b * (K * C) + t];
        S[0][t] = s;
    }
    __syncthreads();
    if (t < C) {
        const int c = t;
        float v[K];
        float m = -3.402823466e38f;
        #pragma unroll
        for (int k = 0; k < K; ++k) { v[k] = S[k][c]; m = fmaxf(m, v[k]); }
        float sum = 0.0f;
        #pragma unroll
        for (int k = 0; k < K; ++k) { v[k] = expf(v[k] - m); sum += v[k]; }
        const float r = 1.0f / sum;
        #pragma unroll
        for (int k = 0; k < K; ++k) {
            const float wv = v[k] * r;
            wd[c * K + k] = wv;
            awdT[k * C + c] = a_p[k] * wv;
        }
    }
}

// ---------------------------------------------------------------------------
// K3: w_e[n][k] = softmax_k( sum_c y[c][n] * wd[c][k] )  (no LDS staging of
// y: each element is read exactly once, stream it)
// ---------------------------------------------------------------------------
__global__ __launch_bounds__(256) void we_kernel(
    const float* __restrict__ y, const float* __restrict__ wd,
    float* __restrict__ we)
{
    __shared__ float wds[C][K];
    const int lane = threadIdx.x & 63;
    const int wave = threadIdx.x >> 6;
    for (int i = threadIdx.x; i < C * K; i += 256) wds[0][i] = wd[i];
    __syncthreads();

    const int n = (blockIdx.x * 4 + wave) * 64 + lane;
    float L[K];
    #pragma unroll
    for (int k = 0; k < K; ++k) L[k] = 0.0f;
    for (int c = 0; c < C; ++c) {
        const float yv = y[c * NPTS + n];
        float wa[K];
        ((float4*)wa)[0] = ((const float4*)&wds[c][0])[0];
        ((float4*)wa)[1] = ((const float4*)&wds[c][0])[1];
        ((float4*)wa)[2] = ((const float4*)&wds[c][0])[2];
        ((float4*)wa)[3] = ((const float4*)&wds[c][0])[3];
        #pragma unroll
        for (int k = 0; k < K; ++k) L[k] = fmaf(yv, wa[k], L[k]);
    }
    float m = L[0];
    #pragma unroll
    for (int k = 1; k < K; ++k) m = fmaxf(m, L[k]);
    float sum = 0.0f;
    #pragma unroll
    for (int k = 0; k < K; ++k) { L[k] = expf(L[k] - m); sum += L[k]; }
    const float r = 1.0f / sum;
    float* dst = we + (size_t)n * K;
    ((float4*)dst)[0] = make_float4(L[0]*r, L[1]*r, L[2]*r, L[3]*r);
    ((float4*)dst)[1] = make_float4(L[4]*r, L[5]*r, L[6]*r, L[7]*r);
    ((float4*)dst)[2] = make_float4(L[8]*r, L[9]*r, L[10]*r, L[11]*r);
    ((float4*)dst)[3] = make_float4(L[12]*r, L[13]*r, L[14]*r, L[15]*r);
}

// ---------------------------------------------------------------------------
// K3b: tabulate F_kc(t) (2-layer PWL map of scalar t) at t=i/NTAB, i=0..NTAB
// ---------------------------------------------------------------------------
__global__ __launch_bounds__(64) void tab_kernel(
    const float* __restrict__ awdT, const float* __restrict__ b_p,
    const float* __restrict__ Ww1, const float* __restrict__ bw1,
    const float* __restrict__ Ww2, const float* __restrict__ bw2,
    const float* __restrict__ gw1, const float* __restrict__ bw1b,
    const float* __restrict__ gw2, const float* __restrict__ bw2b,
    float* __restrict__ tab)
{
    const int lane = threadIdx.x;
    const int k  = blockIdx.y;
    const int i0 = blockIdx.x * 16;

    const float aw = awdT[k * C + lane];
    const float bp = b_p[k * C + lane];
    const float gs1 = gw1[lane] * BN_INV, bb1 = bw1b[lane], bw1c = bw1[lane];
    const float gs2 = gw2[lane] * BN_INV, bb2 = bw2b[lane], bw2c = bw2[lane];

    float w1c[C], w2c[C];
    #pragma unroll
    for (int c = 0; c < C; ++c) { w1c[c] = Ww1[c * C + lane]; w2c[c] = Ww2[c * C + lane]; }

    __shared__ float hs[16][C];

    #pragma unroll
    for (int r = 0; r < 16; ++r) {
        const float t = (float)(i0 + r) * (1.0f / NTAB);
        const float wv = fmaf(bp, t, aw);
        hs[r][lane] = fmaxf(fmaf(wv, gs1, bb1), 0.0f);
    }
    __syncthreads();

    float o[16];
    #pragma unroll
    for (int r = 0; r < 16; ++r) o[r] = bw1c;
    #pragma unroll
    for (int c4 = 0; c4 < 16; ++c4) {
        #pragma unroll
        for (int r = 0; r < 16; ++r) {
            const float4 hv = *(const float4*)&hs[r][c4 * 4];
            o[r] = fmaf(hv.x, w1c[c4 * 4 + 0], o[r]);
            o[r] = fmaf(hv.y, w1c[c4 * 4 + 1], o[r]);
            o[r] = fmaf(hv.z, w1c[c4 * 4 + 2], o[r]);
            o[r] = fmaf(hv.w, w1c[c4 * 4 + 3], o[r]);
        }
    }
    __syncthreads();
    #pragma unroll
    for (int r = 0; r < 16; ++r)
        hs[r][lane] = fmaxf(fmaf(o[r], gs2, bb2), 0.0f);
    __syncthreads();
    #pragma unroll
    for (int r = 0; r < 16; ++r) o[r] = bw2c;
    #pragma unroll
    for (int c4 = 0; c4 < 16; ++c4) {
        #pragma unroll
        for (int r = 0; r < 16; ++r) {
            const float4 hv = *(const float4*)&hs[r][c4 * 4];
            o[r] = fmaf(hv.x, w2c[c4 * 4 + 0], o[r]);
            o[r] = fmaf(hv.y, w2c[c4 * 4 + 1], o[r]);
            o[r] = fmaf(hv.z, w2c[c4 * 4 + 2], o[r]);
            o[r] = fmaf(hv.w, w2c[c4 * 4 + 3], o[r]);
        }
    }
    #pragma unroll
    for (int r = 0; r < 16; ++r) {
        const int i = i0 + r;
        if (i <= NTAB) tab[(k * (NTAB + 1) + i) * C + lane] = o[r];
    }
}

// ---------------------------------------------------------------------------
// K4 (hot): per point n (one wave, lane = channel c). Software-pipelined:
// next point's idx/self-xyz/we prefetched one iteration ahead; yv gathers
// issued at loop top via __shfl id broadcast (no LDS round-trip); xyz as one
// packed float4 gather; yv rows in bf16 (halved gather line traffic).
// ---------------------------------------------------------------------------
__global__ __launch_bounds__(256) void main3_kernel(
    const int* __restrict__ idx, const float4* __restrict__ pk,
    const __hip_bfloat16* __restrict__ yvb, const float* __restrict__ we,
    const float* __restrict__ tab, const float* __restrict__ d_p,
    const float* __restrict__ Wa1, const float* __restrict__ ba1,
    const float* __restrict__ ga, const float* __restrict__ bna,
    const float* __restrict__ Wa2, const float* __restrict__ ba2,
    const float* __restrict__ Wp1, const float* __restrict__ bp1,
    const float* __restrict__ gp, const float* __restrict__ bnp,
    const float* __restrict__ Wp2, const float* __restrict__ bp2,
    float* __restrict__ out)
{
    const int lane = threadIdx.x & 63;
    const int wave = threadIdx.x >> 6;

    __shared__ float geo[4][K][8];    // [1..3] af-features, [4..6] pr-features
    __shared__ float prm[36];

    if (threadIdx.x < 36) {
        const int t = threadIdx.x;
        float v;
        if (t < 9)       v = Wa1[t];
        else if (t < 12) v = ba1[t - 9];
        else if (t < 21) v = Wp1[t - 12];
        else if (t < 24) v = bp1[t - 21];
        else if (t < 27) v = ga[t - 24];
        else if (t < 30) v = bna[t - 27];
        else if (t < 33) v = gp[t - 30];
        else             v = bnp[t - 33];
        prm[t] = v;
    }
    __syncthreads();

    const float ba2c = ba2[lane], bp2c = bp2[lane];
    float wa2c[3], wp2c[3];
    #pragma unroll
    for (int d = 0; d < 3; ++d) { wa2c[d] = Wa2[d * C + lane]; wp2c[d] = Wp2[d * C + lane]; }
    float dpk[K];
    #pragma unroll
    for (int k = 0; k < K; ++k) dpk[k] = d_p[k * C + lane];

    const int gw = blockIdx.x * 4 + wave;
    const int nwv = gridDim.x * 4;
    const ushort* __restrict__ yvu_base = (const ushort*)yvb;

    // ---- prologue prefetch ----
    int n = gw;
    int idv = idx[n * K + (lane & 15)];
    float4 self = pk[n];
    float4 wev0 = ((const float4*)(we + (size_t)n * K))[0];
    float4 wev1 = ((const float4*)(we + (size_t)n * K))[1];
    float4 wev2 = ((const float4*)(we + (size_t)n * K))[2];
    float4 wev3 = ((const float4*)(we + (size_t)n * K))[3];

    while (n < NPTS) {
        const int n_next = n + nwv;

        // ---- dependent gathers for current point (issued first) ----
        const float4 nb = pk[idv];
        ushort yvu[K];
        #pragma unroll
        for (int k = 0; k < K; ++k) {
            const int idk = __shfl(idv, k, 64);
            yvu[k] = yvu_base[(size_t)idk * C + lane];
        }

        // ---- table loads (depend only on prefetched we) ----
        float wearr[K];
        ((float4*)wearr)[0] = wev0;
        ((float4*)wearr)[1] = wev1;
        ((float4*)wearr)[2] = wev2;
        ((float4*)wearr)[3] = wev3;
        float tv0[K], tv1[K], fr[K];
        #pragma unroll
        for (int k = 0; k < K; ++k) {
            const float u = wearr[k] * (float)NTAB;
            int ic = (int)u;
            ic = (ic < 0) ? 0 : (ic > NTAB - 1 ? NTAB - 1 : ic);
            fr[k] = u - (float)ic;
            const float* tp = tab + ((size_t)(k * (NTAB + 1) + ic) << 6) + lane;
            tv0[k] = tp[0];
            tv1[k] = tp[C];
        }

        // ---- prefetch next point's independent loads ----
        int idv_n = 0;
        float4 self_n = make_float4(0.f, 0.f, 0.f, 0.f);
        float4 wen0 = self_n, wen1 = self_n, wen2 = self_n, wen3 = self_n;
        if (n_next < NPTS) {
            idv_n  = idx[n_next * K + (lane & 15)];
            self_n = pk[n_next];
            wen0 = ((const float4*)(we + (size_t)n_next * K))[0];
            wen1 = ((const float4*)(we + (size_t)n_next * K))[1];
            wen2 = ((const float4*)(we + (size_t)n_next * K))[2];
            wen3 = ((const float4*)(we + (size_t)n_next * K))[3];
        }

        // ---- geometry (all lanes compute for k = lane&15; lanes<16 write) ----
        {
            const float px = nb.x - self.x;
            const float py = nb.y - self.y;
            const float pz = nb.z - self.z;
            const float ed  = sqrtf(px * px + py * py + pz * pz);
            const float exy = sqrtf(px * px + py * py);
            const float cose = safediv_n2n(exy, ed);
            const float cosa = safediv_n2n(py, exy);
            float gv[6];
            #pragma unroll
            for (int d = 0; d < 3; ++d) {
                const float a = ed * prm[d] + cosa * prm[3 + d] + cose * prm[6 + d] + prm[9 + d];
                gv[d] = fmaxf(a * (prm[24 + d] * BN_INV) + prm[27 + d], 0.0f);
                const float p = px * prm[12 + d] + py * prm[15 + d] + pz * prm[18 + d] + prm[21 + d];
                gv[3 + d] = fmaxf(p * (prm[30 + d] * BN_INV) + prm[33 + d], 0.0f);
            }
            if (lane < K) {
                float* g = &geo[wave][lane][0];
                g[1] = gv[0]; g[2] = gv[1]; g[3] = gv[2];
                g[4] = gv[3]; g[5] = gv[4]; g[6] = gv[5];
            }
        }

        // ---- w2 lerp + softmax over k ----
        float w2[K];
        #pragma unroll
        for (int k = 0; k < K; ++k) w2[k] = fmaf(fr[k], tv1[k] - tv0[k], tv0[k]);
        float m = w2[0];
        #pragma unroll
        for (int k = 1; k < K; ++k) m = fmaxf(m, w2[k]);
        float sum = 0.0f;
        #pragma unroll
        for (int k = 0; k < K; ++k) { w2[k] = __expf(w2[k] - m); sum += w2[k]; }
        const float r = 1.0f / sum;

        // ---- epilogue ----
        float acc = 0.0f;
        #pragma unroll
        for (int k = 0; k < K; ++k) {
            const float4 g0 = *(const float4*)&geo[wave][k][0];
            const float4 g1 = *(const float4*)&geo[wave][k][4];
            const float afc = fmaf(g0.y, wa2c[0], fmaf(g0.z, wa2c[1], fmaf(g0.w, wa2c[2], ba2c)));
            float prc = fmaf(g1.x, wp2c[0], fmaf(g1.y, wp2c[1], fmaf(g1.z, wp2c[2], bp2c)));
            prc = fmaf(dpk[k], afc, prc);
            const float yvf = __uint_as_float((unsigned)yvu[k] << 16);
            acc = fmaf(yvf + prc, w2[k] * r, acc);
        }
        out[(size_t)n * C + lane] = acc;

        // ---- rotate pipeline ----
        n = n_next;
        idv = idv_n;
        self = self_n;
        wev0 = wen0; wev1 = wen1; wev2 = wen2; wev3 = wen3;
    }
}

// ---------------------------------------------------------------------------
extern "C" void kernel_launch(void* const* d_in, const int* in_sizes, int n_in,
                              void* d_out, int out_size, void* d_ws, size_t ws_size,
                              hipStream_t stream)
{
    (void)in_sizes; (void)n_in; (void)out_size; (void)ws_size;
    const float* x     = (const float*)d_in[0];
    const float* y     = (const float*)d_in[1];
    const float* y_xyz = (const float*)d_in[2];
    const int*   idx   = (const int*)d_in[3];
    const float* Wq = (const float*)d_in[4];  const float* bq = (const float*)d_in[5];
    const float* Wk = (const float*)d_in[6];  const float* bk = (const float*)d_in[7];
    const float* Wv = (const float*)d_in[8];  const float* bv = (const float*)d_in[9];
    const float* Wu = (const float*)d_in[10]; const float* bu = (const float*)d_in[11];
    const float* gu = (const float*)d_in[12]; const float* bnu = (const float*)d_in[13];
    const float* Wp1 = (const float*)d_in[14]; const float* bp1 = (const float*)d_in[15];
    const float* gp  = (const float*)d_in[16]; const float* bnp = (const float*)d_in[17];
    const float* Wp2 = (const float*)d_in[18]; const float* bp2 = (const float*)d_in[19];
    const float* Wa1 = (const float*)d_in[20]; const float* ba1 = (const float*)d_in[21];
    const float* ga  = (const float*)d_in[22]; const float* bna = (const float*)d_in[23];
    const float* Wa2 = (const float*)d_in[24]; const float* ba2 = (const float*)d_in[25];
    const float* gw1 = (const float*)d_in[26]; const float* bw1b = (const float*)d_in[27];
    const float* Ww1 = (const float*)d_in[28]; const float* bw1 = (const float*)d_in[29];
    const float* gw2 = (const float*)d_in[30]; const float* bw2b = (const float*)d_in[31];
    const float* Ww2 = (const float*)d_in[32]; const float* bw2 = (const float*)d_in[33];
    const float* a_p = (const float*)d_in[34];
    const float* b_p = (const float*)d_in[35];
    const float* d_p = (const float*)d_in[36];
    float* out = (float*)d_out;

    float* ws = (float*)d_ws;
    // layout (floats): xq 2M | yk 2M | yv(bf16) 1M | pk 128K(f4) | xu 32K |
    //                  partG 512K | part2 64K | wd 1K | awdT 1K   = ~24 MB
    float* xq    = ws;                            // dead after sred
    float* we    = ws;                            // aliases xq (written later)
    float* yk    = ws + 2097152;                  // dead after sred
    float* tab   = ws + 2097152;                  // aliases yk (written later)
    __hip_bfloat16* yvb = (__hip_bfloat16*)(ws + 2 * 2097152);
    float4* pk   = (float4*)(ws + 2 * 2097152 + 1048576);
    float* xu    = ws + 2 * 2097152 + 1048576 + 131072;
    float* partG = xu + NPTS;                     // 512*1024
    float* part2 = partG + NB2 * K * C;           // 64*1024
    float* wd    = part2 + NB2R * K * C;          // 1024
    float* awdT  = wd + C * K;                    // 1024

    proj_kernel<<<dim3(NPTS / 64, 4), 256, 0, stream>>>(
        x, y, y_xyz, Wq, bq, Wk, bk, Wv, bv, Wu, bu, gu, bnu,
        xq, yk, yvb, xu, pk);
    sred_kernel<<<NB2, 256, 0, stream>>>(xq, yk, xu, idx, partG);
    sred2_kernel<<<NB2R, 1024, 0, stream>>>(partG, part2);
    wd_kernel<<<1, 1024, 0, stream>>>(part2, a_p, wd, awdT);
    we_kernel<<<NPTS / 256, 256, 0, stream>>>(y, wd, we);
    tab_kernel<<<dim3(33, 16), 64, 0, stream>>>(awdT, b_p, Ww1, bw1, Ww2, bw2,
                                                gw1, bw1b, gw2, bw2b, tab);
    main3_kernel<<<2048, 256, 0, stream>>>(idx, pk, yvb, we, tab, d_p,
        Wa1, ba1, ga, bna, Wa2, ba2, Wp1, bp1, gp, bnp, Wp2, bp2, out);
}